// Round 2
// 164.009 us; speedup vs baseline: 1.0196x; 1.0196x over previous
//
#include <hip/hip_runtime.h>
#include <hip/hip_bf16.h>

// Problem: B=8, N=1024, DQ=DK=DV=256, H=8, head_dim=32.
// Pipeline (all bf16 MFMA, fp32 accum):
//   K0 wtrans : W[k][n] f32 -> WT[n][k] bf16 (LDS tile transpose, coalesced both ways)
//   K1 proj   : q=(Q@Wq+bq)*mask, k=(K@Wk+bk)*mask, v=(K@Wv+bv)*mask
//               q,k stored [b][h][n][32] bf16 ; v stored transposed [b][h][32][n]
//   K2 attn   : split-K flash-style, no max subtraction; key loop bounded by len;
//               wave-private P tile (no block barriers in the loop), padded stride;
//               V-fragment loads hoisted above the P waitcnt (latency overlap)
//   K3 fused  : LN0(g0,b0) -> x (LDS, bf16); y = x + relu(x@Wo+bo); out = LN1(y)
//               grid 512 x 16-row blocks (2 blocks/CU vs old 1)

typedef __attribute__((ext_vector_type(8))) short short8;
typedef __attribute__((ext_vector_type(4))) short short4v;
typedef __attribute__((ext_vector_type(4))) float f32x4;

__device__ __forceinline__ short f2bf(float f) {
    union { float f; unsigned u; } x; x.f = f;
    unsigned r = x.u + 0x7fffu + ((x.u >> 16) & 1u);   // RNE
    return (short)(r >> 16);
}
__device__ __forceinline__ float bf2f(short s) {
    union { unsigned u; float f; } x; x.u = ((unsigned)(unsigned short)s) << 16;
    return x.f;
}

// ---------------- K0: transpose + convert weights (coalesced via LDS) ----------------
// grid (16, 4): x = 64x64 tile (4x4 tiling of 256x256), y = which matrix. 256 threads.
__global__ __launch_bounds__(256) void wtrans_kernel(
    const float* __restrict__ Wq, const float* __restrict__ Wk,
    const float* __restrict__ Wv, const float* __restrict__ Wo,
    short* __restrict__ WqT, short* __restrict__ WkT,
    short* __restrict__ WvT, short* __restrict__ WoT)
{
    __shared__ short tile[64][72];                 // +8 pad: breaks pow2 stride
    const float* W; short* T;
    switch (blockIdx.y) {
        case 0:  W = Wq; T = WqT; break;
        case 1:  W = Wk; T = WkT; break;
        case 2:  W = Wv; T = WvT; break;
        default: W = Wo; T = WoT; break;
    }
    const int k0 = (blockIdx.x >> 2) * 64;         // source row tile
    const int n0 = (blockIdx.x & 3) * 64;          // source col tile
    const int c  = threadIdx.x & 63;
    const int r4 = threadIdx.x >> 6;
    #pragma unroll
    for (int i = 0; i < 16; i++) {
        int k = r4 + i * 4;
        tile[k][c] = f2bf(W[(size_t)(k0 + k) * 256 + n0 + c]);   // coalesced read
    }
    __syncthreads();
    #pragma unroll
    for (int i = 0; i < 16; i++) {
        int n = r4 + i * 4;
        T[(size_t)(n0 + n) * 256 + k0 + c] = tile[c][n];         // coalesced write
    }
}

// ---------------- K1: q/k/v projections ----------------
// grid (256, 3) blocks of 256. Block: 32 token rows x 256 cols.
// Wave: 16 rows x 128 cols (rh = wid>>1 row-half, ch = wid&1 col-half).
__global__ __launch_bounds__(256) void proj_kernel(
    const float* __restrict__ Q, const float* __restrict__ Kin,
    const short* __restrict__ WqT, const short* __restrict__ WkT, const short* __restrict__ WvT,
    const float* __restrict__ bq, const float* __restrict__ bk, const float* __restrict__ bv,
    const int* __restrict__ lengths,
    short* __restrict__ qb, short* __restrict__ kb, short* __restrict__ vT)
{
    const int which = blockIdx.y;                 // 0=q,1=k,2=v
    const float* A    = (which == 0) ? Q   : Kin;
    const short* WT   = (which == 0) ? WqT : (which == 1) ? WkT : WvT;
    const float* bias = (which == 0) ? bq  : (which == 1) ? bk  : bv;

    const int tid = threadIdx.x;
    const int lane = tid & 63, wid = tid >> 6;
    const int m = lane & 15, quad = lane >> 4;
    const int rh = wid >> 1, ch = wid & 1;
    const int r0 = blockIdx.x * 32 + rh * 16;     // wave's token row base (global)
    const int c0 = ch * 128;                      // wave's column base
    const int b = blockIdx.x >> 5;                // batch (32 rows/block, 32 blocks/batch)
    const int len = lengths[b];
    const int ntok0 = r0 & 1023;                  // within-batch row base

    f32x4 acc[8];
    #pragma unroll
    for (int t = 0; t < 8; t++) acc[t] = (f32x4){0.f, 0.f, 0.f, 0.f};

    if (ntok0 < len) {                            // fully-masked tiles: skip GEMM
        const float* arow = A + (size_t)(r0 + m) * 256;
        for (int kk = 0; kk < 256; kk += 32) {
            const float* ap = arow + kk + quad * 8;
            float4 f0 = *(const float4*)(ap);
            float4 f1 = *(const float4*)(ap + 4);
            short8 af;
            af[0] = f2bf(f0.x); af[1] = f2bf(f0.y); af[2] = f2bf(f0.z); af[3] = f2bf(f0.w);
            af[4] = f2bf(f1.x); af[5] = f2bf(f1.y); af[6] = f2bf(f1.z); af[7] = f2bf(f1.w);
            #pragma unroll
            for (int t = 0; t < 8; t++) {
                short8 bf = *(const short8*)(WT + (c0 + t * 16 + m) * 256 + kk + quad * 8);
                acc[t] = __builtin_amdgcn_mfma_f32_16x16x32_bf16(af, bf, acc[t], 0, 0, 0);
            }
        }
    }

    #pragma unroll
    for (int t = 0; t < 8; t++) {
        int n = c0 + t * 16 + m;                   // output column
        float bv_ = bias[n];
        int h = n >> 5, i = n & 31;
        int bh = b * 8 + h;
        #pragma unroll
        for (int reg = 0; reg < 4; reg++) {
            int ntok = ntok0 + quad * 4 + reg;     // C layout: row = quad*4+reg
            float val = (ntok < len) ? (acc[t][reg] + bv_) : 0.f;
            short s = f2bf(val);
            if (which == 2) {
                vT[(size_t)(bh * 32 + i) * 1024 + ntok] = s;
            } else {
                short* dst = (which == 0) ? qb : kb;
                dst[((size_t)bh * 1024 + ntok) * 32 + i] = s;
            }
        }
    }
}

// ---------------- K2: attention ----------------
// grid (32, 64): x = q-tile (32 rows), y = b*8+h. Block 256 = 4 waves.
// Wave (qh, ks): q-rows [qr0, qr0+16), keys [ks*512, ks*512+512) bounded by len.
// No barriers in the key loop (P is wave-private); one barrier for split-K combine.
__global__ __launch_bounds__(256) void attn_kernel(
    const short* __restrict__ qb, const short* __restrict__ kb, const short* __restrict__ vT,
    const int* __restrict__ lengths, float* __restrict__ O1)
{
    __shared__ short P[4][16][72];                 // per-wave P tile, padded (72 shorts/row)
    __shared__ float cbO[2][16][33];               // split-K partial O from ks=1 waves
    __shared__ float cbL[2][16];                   // split-K partial rowsums
    const int tid = threadIdx.x;
    const int lane = tid & 63, wid = tid >> 6;
    const int m = lane & 15, quad = lane >> 4;
    const int ks = wid & 1, qh = wid >> 1;
    const int bh = blockIdx.y;
    const int b = bh >> 3, h = bh & 7;
    const int len = lengths[b];
    const int qr0 = blockIdx.x * 32 + qh * 16;

    const short* qbase = qb + (size_t)bh * 1024 * 32;
    const short* kbase = kb + (size_t)bh * 1024 * 32;
    const short* vbase = vT + (size_t)bh * 32 * 1024;

    // A-frag of q: rows qr0..qr0+15, k-dim 32 == one MFMA K step. Load once.
    const short8 qf = *(const short8*)(qbase + (qr0 + m) * 32 + quad * 8);

    f32x4 o0 = (f32x4){0.f, 0.f, 0.f, 0.f};       // vdims 0..15
    f32x4 o1 = (f32x4){0.f, 0.f, 0.f, 0.f};       // vdims 16..31
    float l[4] = {0.f, 0.f, 0.f, 0.f};            // rowsum partials (row = quad*4+reg)

    const int kbeg = ks * 512;
    int kchunks = 0;
    if (qr0 < len && len > kbeg) {
        int rem = len - kbeg;
        kchunks = rem >= 512 ? 8 : ((rem + 63) >> 6);
    }

    for (int ci = 0; ci < kchunks; ci++) {
        int key0 = kbeg + ci * 64;
        // V fragments are independent of P: issue them now so their L2 latency
        // hides under the QK^T + exp + P-write phase instead of after the waitcnt.
        short8 vf0a = *(const short8*)(vbase + (size_t)(m) * 1024      + key0 + quad * 8);
        short8 vf1a = *(const short8*)(vbase + (size_t)(16 + m) * 1024 + key0 + quad * 8);
        short8 vf0b = *(const short8*)(vbase + (size_t)(m) * 1024      + key0 + 32 + quad * 8);
        short8 vf1b = *(const short8*)(vbase + (size_t)(16 + m) * 1024 + key0 + 32 + quad * 8);
        #pragma unroll
        for (int t = 0; t < 4; t++) {
            short8 kf = *(const short8*)(kbase + (key0 + t * 16 + m) * 32 + quad * 8);
            f32x4 s = __builtin_amdgcn_mfma_f32_16x16x32_bf16(qf, kf,
                        (f32x4){0.f, 0.f, 0.f, 0.f}, 0, 0, 0);
            int col = key0 + t * 16 + m;           // key index (C layout col)
            bool cm = col < len;
            #pragma unroll
            for (int reg = 0; reg < 4; reg++) {
                float e = cm ? __expf(s[reg] * 0.0625f) : 0.f;   // /sqrt(256)
                l[reg] += e;
                P[wid][quad * 4 + reg][t * 16 + m] = f2bf(e);
            }
        }
        // wave-private tile: per-wave LDS ordering only, no block barrier
        asm volatile("s_waitcnt lgkmcnt(0)" ::: "memory");
        short8 pf0 = *(const short8*)(&P[wid][m][quad * 8]);
        short8 pf1 = *(const short8*)(&P[wid][m][32 + quad * 8]);
        o0 = __builtin_amdgcn_mfma_f32_16x16x32_bf16(pf0, vf0a, o0, 0, 0, 0);
        o1 = __builtin_amdgcn_mfma_f32_16x16x32_bf16(pf0, vf1a, o1, 0, 0, 0);
        o0 = __builtin_amdgcn_mfma_f32_16x16x32_bf16(pf1, vf0b, o0, 0, 0, 0);
        o1 = __builtin_amdgcn_mfma_f32_16x16x32_bf16(pf1, vf1b, o1, 0, 0, 0);
    }

    // reduce rowsums across the 16 lanes of each quad group
    #pragma unroll
    for (int reg = 0; reg < 4; reg++) {
        float s = l[reg];
        s += __shfl_xor(s, 1); s += __shfl_xor(s, 2);
        s += __shfl_xor(s, 4); s += __shfl_xor(s, 8);
        l[reg] = s;
    }

    // split-K combine: ks=1 publishes partials, ks=0 merges + writes out
    if (ks == 1) {
        #pragma unroll
        for (int reg = 0; reg < 4; reg++) {
            cbO[qh][quad * 4 + reg][m]      = o0[reg];
            cbO[qh][quad * 4 + reg][16 + m] = o1[reg];
        }
        if (m == 0) {
            #pragma unroll
            for (int reg = 0; reg < 4; reg++) cbL[qh][quad * 4 + reg] = l[reg];
        }
    }
    __syncthreads();
    if (ks == 0) {
        const int hbase = h * 32;
        #pragma unroll
        for (int reg = 0; reg < 4; reg++) {
            int r = quad * 4 + reg;
            o0[reg] += cbO[qh][r][m];
            o1[reg] += cbO[qh][r][16 + m];
            float lt = l[reg] + cbL[qh][r];
            int qrow = qr0 + r;                    // within-batch row
            float f = (qrow < len) ? 1.f / (lt + 1e-15f) : 0.f;
            size_t obase = ((size_t)(b * 1024 + qrow)) * 256 + hbase;
            float q0 = bf2f(qbase[qrow * 32 + m]);
            float q1 = bf2f(qbase[qrow * 32 + 16 + m]);
            O1[obase + m]      = q0 + o0[reg] * f;
            O1[obase + 16 + m] = q1 + o1[reg] * f;
        }
    }
}

// ---------------- K3: fused LN0 + output projection + relu residual + LN1 ----------------
// grid 512 blocks of 256 (4 waves). Block: 16 token rows x full 256 cols.
// Phase 1: LN0 from O1 -> normalized bf16 x staged in LDS (no global Xb).
// Phase 2: GEMM x@Wo from LDS A-fragments; wave = 16 rows x 64 cols (c0 = wid*64).
// Phase 3: y = x + relu(c+bo); LN1 row stats across 4 col-quarter waves via LDS.
__global__ __launch_bounds__(256) void out_kernel(
    const float* __restrict__ O1, const short* __restrict__ WoT,
    const float* __restrict__ g0, const float* __restrict__ b0,
    const float* __restrict__ bo, const float* __restrict__ g1, const float* __restrict__ b1,
    float* __restrict__ out)
{
    __shared__ short Xs[16][264];                  // normalized x, bf16, padded stride
    __shared__ float st[4][2][16];                 // [wave][{s1,s2}][row]
    const int tid = threadIdx.x;
    const int r0 = blockIdx.x * 16;

    // ---- Phase 1: LN0. 16 threads per row, 16 cols per thread. ----
    {
        const int lrow  = tid >> 4;                // 0..15
        const int cbase = (tid & 15) * 16;
        const float* rowp = O1 + (size_t)(r0 + lrow) * 256 + cbase;
        float4 a0 = ((const float4*)rowp)[0];
        float4 a1 = ((const float4*)rowp)[1];
        float4 a2 = ((const float4*)rowp)[2];
        float4 a3 = ((const float4*)rowp)[3];
        float s  = a0.x + a0.y + a0.z + a0.w + a1.x + a1.y + a1.z + a1.w
                 + a2.x + a2.y + a2.z + a2.w + a3.x + a3.y + a3.z + a3.w;
        float s2 = a0.x*a0.x + a0.y*a0.y + a0.z*a0.z + a0.w*a0.w
                 + a1.x*a1.x + a1.y*a1.y + a1.z*a1.z + a1.w*a1.w
                 + a2.x*a2.x + a2.y*a2.y + a2.z*a2.z + a2.w*a2.w
                 + a3.x*a3.x + a3.y*a3.y + a3.z*a3.z + a3.w*a3.w;
        // reduce across the 16 lanes of this row (lanes are 16-aligned groups)
        s  += __shfl_xor(s, 1);  s  += __shfl_xor(s, 2);
        s  += __shfl_xor(s, 4);  s  += __shfl_xor(s, 8);
        s2 += __shfl_xor(s2, 1); s2 += __shfl_xor(s2, 2);
        s2 += __shfl_xor(s2, 4); s2 += __shfl_xor(s2, 8);
        float mean = s * (1.f / 256.f);
        float var  = s2 * (1.f / 256.f) - mean * mean;
        float rs = rsqrtf(var + 1e-5f);
        float4 g0a = ((const float4*)(g0 + cbase))[0];
        float4 g0b = ((const float4*)(g0 + cbase))[1];
        float4 g0c = ((const float4*)(g0 + cbase))[2];
        float4 g0d = ((const float4*)(g0 + cbase))[3];
        float4 b0a = ((const float4*)(b0 + cbase))[0];
        float4 b0b = ((const float4*)(b0 + cbase))[1];
        float4 b0c = ((const float4*)(b0 + cbase))[2];
        float4 b0d = ((const float4*)(b0 + cbase))[3];
        short8 y0, y1;
        y0[0] = f2bf((a0.x - mean) * rs * g0a.x + b0a.x);
        y0[1] = f2bf((a0.y - mean) * rs * g0a.y + b0a.y);
        y0[2] = f2bf((a0.z - mean) * rs * g0a.z + b0a.z);
        y0[3] = f2bf((a0.w - mean) * rs * g0a.w + b0a.w);
        y0[4] = f2bf((a1.x - mean) * rs * g0b.x + b0b.x);
        y0[5] = f2bf((a1.y - mean) * rs * g0b.y + b0b.y);
        y0[6] = f2bf((a1.z - mean) * rs * g0b.z + b0b.z);
        y0[7] = f2bf((a1.w - mean) * rs * g0b.w + b0b.w);
        y1[0] = f2bf((a2.x - mean) * rs * g0c.x + b0c.x);
        y1[1] = f2bf((a2.y - mean) * rs * g0c.y + b0c.y);
        y1[2] = f2bf((a2.z - mean) * rs * g0c.z + b0c.z);
        y1[3] = f2bf((a2.w - mean) * rs * g0c.w + b0c.w);
        y1[4] = f2bf((a3.x - mean) * rs * g0d.x + b0d.x);
        y1[5] = f2bf((a3.y - mean) * rs * g0d.y + b0d.y);
        y1[6] = f2bf((a3.z - mean) * rs * g0d.z + b0d.z);
        y1[7] = f2bf((a3.w - mean) * rs * g0d.w + b0d.w);
        *(short8*)(&Xs[lrow][cbase])     = y0;
        *(short8*)(&Xs[lrow][cbase + 8]) = y1;
    }
    __syncthreads();

    // ---- Phase 2: GEMM from LDS. Wave covers 16 rows x 64 cols. ----
    const int lane = tid & 63, wid = tid >> 6;
    const int m = lane & 15, quad = lane >> 4;
    const int c0 = wid * 64;

    f32x4 acc[4];
    #pragma unroll
    for (int t = 0; t < 4; t++) acc[t] = (f32x4){0.f, 0.f, 0.f, 0.f};

    for (int kk = 0; kk < 256; kk += 32) {
        short8 af = *(const short8*)(&Xs[m][kk + quad * 8]);
        #pragma unroll
        for (int t = 0; t < 4; t++) {
            short8 bf = *(const short8*)(WoT + (c0 + t * 16 + m) * 256 + kk + quad * 8);
            acc[t] = __builtin_amdgcn_mfma_f32_16x16x32_bf16(af, bf, acc[t], 0, 0, 0);
        }
    }

    // ---- Phase 3: y = x + relu(c + bo); LN1 stats over this col-quarter ----
    float s1[4] = {0.f, 0.f, 0.f, 0.f};
    float s2v[4] = {0.f, 0.f, 0.f, 0.f};
    #pragma unroll
    for (int t = 0; t < 4; t++) {
        int n = c0 + t * 16 + m;
        float bon = bo[n];
        #pragma unroll
        for (int reg = 0; reg < 4; reg++) {
            int r = quad * 4 + reg;
            float xv = bf2f(Xs[r][n]);
            float c = acc[t][reg] + bon;
            float yv = xv + (c > 0.f ? c : 0.f);
            acc[t][reg] = yv;                       // reuse acc as y storage
            s1[reg] += yv;
            s2v[reg] += yv * yv;
        }
    }
    #pragma unroll
    for (int reg = 0; reg < 4; reg++) {
        float a = s1[reg], bsum = s2v[reg];
        a += __shfl_xor(a, 1); a += __shfl_xor(a, 2); a += __shfl_xor(a, 4); a += __shfl_xor(a, 8);
        bsum += __shfl_xor(bsum, 1); bsum += __shfl_xor(bsum, 2); bsum += __shfl_xor(bsum, 4); bsum += __shfl_xor(bsum, 8);
        s1[reg] = a; s2v[reg] = bsum;
    }
    if (m == 0) {
        #pragma unroll
        for (int reg = 0; reg < 4; reg++) {
            st[wid][0][quad * 4 + reg] = s1[reg];
            st[wid][1][quad * 4 + reg] = s2v[reg];
        }
    }
    __syncthreads();
    #pragma unroll
    for (int reg = 0; reg < 4; reg++) {
        int r = quad * 4 + reg;
        float t1 = st[0][0][r] + st[1][0][r] + st[2][0][r] + st[3][0][r];
        float t2 = st[0][1][r] + st[1][1][r] + st[2][1][r] + st[3][1][r];
        float mean = t1 * (1.f / 256.f);
        float var  = t2 * (1.f / 256.f) - mean * mean;
        float rs = rsqrtf(var + 1e-5f);
        int token = r0 + r;
        #pragma unroll
        for (int t = 0; t < 4; t++) {
            int n = c0 + t * 16 + m;
            out[(size_t)token * 256 + n] = (acc[t][reg] - mean) * rs * g1[n] + b1[n];
        }
    }
}

extern "C" void kernel_launch(void* const* d_in, const int* in_sizes, int n_in,
                              void* d_out, int out_size, void* d_ws, size_t ws_size,
                              hipStream_t stream) {
    const float* Q   = (const float*)d_in[0];
    const float* K   = (const float*)d_in[1];
    const int* lengths = (const int*)d_in[2];
    const float* Wq  = (const float*)d_in[3];
    const float* bq  = (const float*)d_in[4];
    const float* Wk  = (const float*)d_in[5];
    const float* bk  = (const float*)d_in[6];
    const float* Wv  = (const float*)d_in[7];
    const float* bv  = (const float*)d_in[8];
    const float* Wo  = (const float*)d_in[9];
    const float* bo  = (const float*)d_in[10];
    const float* g0  = (const float*)d_in[11];
    const float* b0  = (const float*)d_in[12];
    const float* g1  = (const float*)d_in[13];
    const float* b1  = (const float*)d_in[14];
    float* out = (float*)d_out;

    char* ws = (char*)d_ws;
    short* qb  = (short*)(ws);                         // [8][8][1024][32] bf16, 4 MB
    short* kb  = (short*)(ws + (4u << 20));            // 4 MB
    short* vT  = (short*)(ws + (8u << 20));            // [8][8][32][1024] bf16, 4 MB
    float* O1  = (float*)(ws + (12u << 20));           // [8192][256] f32, 8 MB
    short* WqT = (short*)(ws + (20u << 20));           // 128 KB each, [n][k] bf16
    short* WkT = (short*)(ws + (20u << 20) + (128u << 10));
    short* WvT = (short*)(ws + (20u << 20) + (256u << 10));
    short* WoT = (short*)(ws + (20u << 20) + (384u << 10));

    wtrans_kernel<<<dim3(16, 4), 256, 0, stream>>>(Wq, Wk, Wv, Wo, WqT, WkT, WvT, WoT);
    proj_kernel<<<dim3(256, 3), 256, 0, stream>>>(Q, K, WqT, WkT, WvT, bq, bk, bv,
                                                  lengths, qb, kb, vT);
    attn_kernel<<<dim3(32, 64), 256, 0, stream>>>(qb, kb, vT, lengths, O1);
    out_kernel<<<dim3(512), 256, 0, stream>>>(O1, WoT, g0, b0, bo, g1, b1, out);
}

// Round 3
// 159.685 us; speedup vs baseline: 1.0472x; 1.0271x over previous
//
#include <hip/hip_runtime.h>
#include <hip/hip_bf16.h>

// Problem: B=8, N=1024, DQ=DK=DV=256, H=8, head_dim=32.
// Pipeline (all bf16 MFMA, fp32 accum):
//   K0 wtrans : W[k][n] f32 -> WT[n][k] bf16 (LDS tile transpose, coalesced both ways)
//   K1 proj   : y=0: q=(Q@Wq+bq)*mask ; y=1: k AND v from one pass over K
//               (A loaded+converted once, fed to two weight matrices)
//               q,k stored [b][h][n][32] bf16 ; v stored transposed [b][h][32][n]
//   K2 attn   : split-K flash-style, parity-interleaved chunks (balanced for any len);
//               wave-private P tile (no block barriers in the loop), padded stride;
//               V-fragment loads hoisted above the P waitcnt (latency overlap)
//   K3 fused  : LN0(g0,b0) -> x (LDS, bf16); y = x + relu(x@Wo+bo); out = LN1(y)

typedef __attribute__((ext_vector_type(8))) short short8;
typedef __attribute__((ext_vector_type(4))) short short4v;
typedef __attribute__((ext_vector_type(4))) float f32x4;

__device__ __forceinline__ short f2bf(float f) {
    union { float f; unsigned u; } x; x.f = f;
    unsigned r = x.u + 0x7fffu + ((x.u >> 16) & 1u);   // RNE
    return (short)(r >> 16);
}
__device__ __forceinline__ float bf2f(short s) {
    union { unsigned u; float f; } x; x.u = ((unsigned)(unsigned short)s) << 16;
    return x.f;
}

// ---------------- K0: transpose + convert weights (coalesced via LDS) ----------------
// grid (16, 4): x = 64x64 tile (4x4 tiling of 256x256), y = which matrix. 256 threads.
__global__ __launch_bounds__(256) void wtrans_kernel(
    const float* __restrict__ Wq, const float* __restrict__ Wk,
    const float* __restrict__ Wv, const float* __restrict__ Wo,
    short* __restrict__ WqT, short* __restrict__ WkT,
    short* __restrict__ WvT, short* __restrict__ WoT)
{
    __shared__ short tile[64][72];                 // +8 pad: breaks pow2 stride
    const float* W; short* T;
    switch (blockIdx.y) {
        case 0:  W = Wq; T = WqT; break;
        case 1:  W = Wk; T = WkT; break;
        case 2:  W = Wv; T = WvT; break;
        default: W = Wo; T = WoT; break;
    }
    const int k0 = (blockIdx.x >> 2) * 64;         // source row tile
    const int n0 = (blockIdx.x & 3) * 64;          // source col tile
    const int c  = threadIdx.x & 63;
    const int r4 = threadIdx.x >> 6;
    #pragma unroll
    for (int i = 0; i < 16; i++) {
        int k = r4 + i * 4;
        tile[k][c] = f2bf(W[(size_t)(k0 + k) * 256 + n0 + c]);   // coalesced read
    }
    __syncthreads();
    #pragma unroll
    for (int i = 0; i < 16; i++) {
        int n = r4 + i * 4;
        T[(size_t)(n0 + n) * 256 + k0 + c] = tile[c][n];         // coalesced write
    }
}

// ---------------- K1: projections ----------------
// grid (256, 2) blocks of 256. Block: 32 token rows x 256 cols.
// y=0: q only. y=1: k AND v (A row loaded + converted ONCE, two MFMA chains).
// Wave: 16 rows x 128 cols (rh = wid>>1 row-half, ch = wid&1 col-half).
__global__ __launch_bounds__(256) void proj_kernel(
    const float* __restrict__ Q, const float* __restrict__ Kin,
    const short* __restrict__ WqT, const short* __restrict__ WkT, const short* __restrict__ WvT,
    const float* __restrict__ bq, const float* __restrict__ bk, const float* __restrict__ bv,
    const int* __restrict__ lengths,
    short* __restrict__ qb, short* __restrict__ kb, short* __restrict__ vT)
{
    const int which = blockIdx.y;                 // 0=q, 1=k+v
    const float* A   = (which == 0) ? Q   : Kin;
    const short* WTa = (which == 0) ? WqT : WkT;

    const int tid = threadIdx.x;
    const int lane = tid & 63, wid = tid >> 6;
    const int m = lane & 15, quad = lane >> 4;
    const int rh = wid >> 1, ch = wid & 1;
    const int r0 = blockIdx.x * 32 + rh * 16;     // wave's token row base (global)
    const int c0 = ch * 128;                      // wave's column base
    const int b = blockIdx.x >> 5;                // batch (32 rows/block, 32 blocks/batch)
    const int len = lengths[b];
    const int ntok0 = r0 & 1023;                  // within-batch row base

    f32x4 accA[8], accB[8];
    #pragma unroll
    for (int t = 0; t < 8; t++) {
        accA[t] = (f32x4){0.f, 0.f, 0.f, 0.f};
        accB[t] = (f32x4){0.f, 0.f, 0.f, 0.f};
    }

    if (ntok0 < len) {                            // fully-masked tiles: skip GEMM
        const float* arow = A + (size_t)(r0 + m) * 256;
        for (int kk = 0; kk < 256; kk += 32) {
            const float* ap = arow + kk + quad * 8;
            float4 f0 = *(const float4*)(ap);
            float4 f1 = *(const float4*)(ap + 4);
            short8 af;
            af[0] = f2bf(f0.x); af[1] = f2bf(f0.y); af[2] = f2bf(f0.z); af[3] = f2bf(f0.w);
            af[4] = f2bf(f1.x); af[5] = f2bf(f1.y); af[6] = f2bf(f1.z); af[7] = f2bf(f1.w);
            #pragma unroll
            for (int t = 0; t < 8; t++) {
                short8 bfa = *(const short8*)(WTa + (c0 + t * 16 + m) * 256 + kk + quad * 8);
                accA[t] = __builtin_amdgcn_mfma_f32_16x16x32_bf16(af, bfa, accA[t], 0, 0, 0);
            }
            if (which == 1) {
                #pragma unroll
                for (int t = 0; t < 8; t++) {
                    short8 bfb = *(const short8*)(WvT + (c0 + t * 16 + m) * 256 + kk + quad * 8);
                    accB[t] = __builtin_amdgcn_mfma_f32_16x16x32_bf16(af, bfb, accB[t], 0, 0, 0);
                }
            }
        }
    }

    #pragma unroll
    for (int t = 0; t < 8; t++) {
        int n = c0 + t * 16 + m;                   // output column
        int h = n >> 5, i = n & 31;
        int bh = b * 8 + h;
        if (which == 0) {
            float bias = bq[n];
            #pragma unroll
            for (int reg = 0; reg < 4; reg++) {
                int ntok = ntok0 + quad * 4 + reg; // C layout: row = quad*4+reg
                float val = (ntok < len) ? (accA[t][reg] + bias) : 0.f;
                qb[((size_t)bh * 1024 + ntok) * 32 + i] = f2bf(val);
            }
        } else {
            float bk_ = bk[n];
            float bv_ = bv[n];
            #pragma unroll
            for (int reg = 0; reg < 4; reg++) {
                int ntok = ntok0 + quad * 4 + reg;
                bool ok = ntok < len;
                float vk = ok ? (accA[t][reg] + bk_) : 0.f;
                float vv = ok ? (accB[t][reg] + bv_) : 0.f;
                kb[((size_t)bh * 1024 + ntok) * 32 + i] = f2bf(vk);
                vT[(size_t)(bh * 32 + i) * 1024 + ntok] = f2bf(vv);
            }
        }
    }
}

// ---------------- K2: attention ----------------
// grid (32, 64): x = q-tile (32 rows), y = b*8+h. Block 256 = 4 waves.
// Wave (qh, ks): q-rows [qr0, qr0+16); key chunks parity-interleaved by ks
// (key0 = (2*ci+ks)*64) so both waves get ceil/floor(nch/2) regardless of len.
// No barriers in the key loop (P is wave-private); one barrier for split-K combine.
__global__ __launch_bounds__(256) void attn_kernel(
    const short* __restrict__ qb, const short* __restrict__ kb, const short* __restrict__ vT,
    const int* __restrict__ lengths, float* __restrict__ O1)
{
    __shared__ short P[4][16][72];                 // per-wave P tile, padded (72 shorts/row)
    __shared__ float cbO[2][16][33];               // split-K partial O from ks=1 waves
    __shared__ float cbL[2][16];                   // split-K partial rowsums
    const int tid = threadIdx.x;
    const int lane = tid & 63, wid = tid >> 6;
    const int m = lane & 15, quad = lane >> 4;
    const int ks = wid & 1, qh = wid >> 1;
    const int bh = blockIdx.y;
    const int b = bh >> 3, h = bh & 7;
    const int len = lengths[b];
    const int qr0 = blockIdx.x * 32 + qh * 16;

    const short* qbase = qb + (size_t)bh * 1024 * 32;
    const short* kbase = kb + (size_t)bh * 1024 * 32;
    const short* vbase = vT + (size_t)bh * 32 * 1024;

    // A-frag of q: rows qr0..qr0+15, k-dim 32 == one MFMA K step. Load once.
    const short8 qf = *(const short8*)(qbase + (qr0 + m) * 32 + quad * 8);

    f32x4 o0 = (f32x4){0.f, 0.f, 0.f, 0.f};       // vdims 0..15
    f32x4 o1 = (f32x4){0.f, 0.f, 0.f, 0.f};       // vdims 16..31
    float l[4] = {0.f, 0.f, 0.f, 0.f};            // rowsum partials (row = quad*4+reg)

    int nch = 0;
    if (qr0 < len) nch = (len + 63) >> 6;          // total 64-key chunks
    const int kchunks = (nch + 1 - ks) >> 1;       // ks=0: ceil(nch/2), ks=1: floor

    for (int ci = 0; ci < kchunks; ci++) {
        int key0 = (ci * 2 + ks) * 64;
        // V fragments are independent of P: issue them now so their L2 latency
        // hides under the QK^T + exp + P-write phase instead of after the waitcnt.
        short8 vf0a = *(const short8*)(vbase + (size_t)(m) * 1024      + key0 + quad * 8);
        short8 vf1a = *(const short8*)(vbase + (size_t)(16 + m) * 1024 + key0 + quad * 8);
        short8 vf0b = *(const short8*)(vbase + (size_t)(m) * 1024      + key0 + 32 + quad * 8);
        short8 vf1b = *(const short8*)(vbase + (size_t)(16 + m) * 1024 + key0 + 32 + quad * 8);
        #pragma unroll
        for (int t = 0; t < 4; t++) {
            short8 kf = *(const short8*)(kbase + (key0 + t * 16 + m) * 32 + quad * 8);
            f32x4 s = __builtin_amdgcn_mfma_f32_16x16x32_bf16(qf, kf,
                        (f32x4){0.f, 0.f, 0.f, 0.f}, 0, 0, 0);
            int col = key0 + t * 16 + m;           // key index (C layout col)
            bool cm = col < len;
            #pragma unroll
            for (int reg = 0; reg < 4; reg++) {
                float e = cm ? __expf(s[reg] * 0.0625f) : 0.f;   // /sqrt(256)
                l[reg] += e;
                P[wid][quad * 4 + reg][t * 16 + m] = f2bf(e);
            }
        }
        // wave-private tile: per-wave LDS ordering only, no block barrier
        asm volatile("s_waitcnt lgkmcnt(0)" ::: "memory");
        short8 pf0 = *(const short8*)(&P[wid][m][quad * 8]);
        short8 pf1 = *(const short8*)(&P[wid][m][32 + quad * 8]);
        o0 = __builtin_amdgcn_mfma_f32_16x16x32_bf16(pf0, vf0a, o0, 0, 0, 0);
        o1 = __builtin_amdgcn_mfma_f32_16x16x32_bf16(pf0, vf1a, o1, 0, 0, 0);
        o0 = __builtin_amdgcn_mfma_f32_16x16x32_bf16(pf1, vf0b, o0, 0, 0, 0);
        o1 = __builtin_amdgcn_mfma_f32_16x16x32_bf16(pf1, vf1b, o1, 0, 0, 0);
    }

    // reduce rowsums across the 16 lanes of each quad group
    #pragma unroll
    for (int reg = 0; reg < 4; reg++) {
        float s = l[reg];
        s += __shfl_xor(s, 1); s += __shfl_xor(s, 2);
        s += __shfl_xor(s, 4); s += __shfl_xor(s, 8);
        l[reg] = s;
    }

    // split-K combine: ks=1 publishes partials, ks=0 merges + writes out
    if (ks == 1) {
        #pragma unroll
        for (int reg = 0; reg < 4; reg++) {
            cbO[qh][quad * 4 + reg][m]      = o0[reg];
            cbO[qh][quad * 4 + reg][16 + m] = o1[reg];
        }
        if (m == 0) {
            #pragma unroll
            for (int reg = 0; reg < 4; reg++) cbL[qh][quad * 4 + reg] = l[reg];
        }
    }
    __syncthreads();
    if (ks == 0) {
        const int hbase = h * 32;
        #pragma unroll
        for (int reg = 0; reg < 4; reg++) {
            int r = quad * 4 + reg;
            o0[reg] += cbO[qh][r][m];
            o1[reg] += cbO[qh][r][16 + m];
            float lt = l[reg] + cbL[qh][r];
            int qrow = qr0 + r;                    // within-batch row
            float f = (qrow < len) ? 1.f / (lt + 1e-15f) : 0.f;
            size_t obase = ((size_t)(b * 1024 + qrow)) * 256 + hbase;
            float q0 = bf2f(qbase[qrow * 32 + m]);
            float q1 = bf2f(qbase[qrow * 32 + 16 + m]);
            O1[obase + m]      = q0 + o0[reg] * f;
            O1[obase + 16 + m] = q1 + o1[reg] * f;
        }
    }
}

// ---------------- K3: fused LN0 + output projection + relu residual + LN1 ----------------
// grid 512 blocks of 256 (4 waves). Block: 16 token rows x full 256 cols.
// Phase 1: LN0 from O1 -> normalized bf16 x staged in LDS (no global Xb).
// Phase 2: GEMM x@Wo from LDS A-fragments; wave = 16 rows x 64 cols (c0 = wid*64).
// Phase 3: y = x + relu(c+bo); LN1 row stats across 4 col-quarter waves via LDS.
__global__ __launch_bounds__(256) void out_kernel(
    const float* __restrict__ O1, const short* __restrict__ WoT,
    const float* __restrict__ g0, const float* __restrict__ b0,
    const float* __restrict__ bo, const float* __restrict__ g1, const float* __restrict__ b1,
    float* __restrict__ out)
{
    __shared__ short Xs[16][264];                  // normalized x, bf16, padded stride
    __shared__ float st[4][2][16];                 // [wave][{s1,s2}][row]
    const int tid = threadIdx.x;
    const int r0 = blockIdx.x * 16;

    // ---- Phase 1: LN0. 16 threads per row, 16 cols per thread. ----
    {
        const int lrow  = tid >> 4;                // 0..15
        const int cbase = (tid & 15) * 16;
        const float* rowp = O1 + (size_t)(r0 + lrow) * 256 + cbase;
        float4 a0 = ((const float4*)rowp)[0];
        float4 a1 = ((const float4*)rowp)[1];
        float4 a2 = ((const float4*)rowp)[2];
        float4 a3 = ((const float4*)rowp)[3];
        float s  = a0.x + a0.y + a0.z + a0.w + a1.x + a1.y + a1.z + a1.w
                 + a2.x + a2.y + a2.z + a2.w + a3.x + a3.y + a3.z + a3.w;
        float s2 = a0.x*a0.x + a0.y*a0.y + a0.z*a0.z + a0.w*a0.w
                 + a1.x*a1.x + a1.y*a1.y + a1.z*a1.z + a1.w*a1.w
                 + a2.x*a2.x + a2.y*a2.y + a2.z*a2.z + a2.w*a2.w
                 + a3.x*a3.x + a3.y*a3.y + a3.z*a3.z + a3.w*a3.w;
        // reduce across the 16 lanes of this row (lanes are 16-aligned groups)
        s  += __shfl_xor(s, 1);  s  += __shfl_xor(s, 2);
        s  += __shfl_xor(s, 4);  s  += __shfl_xor(s, 8);
        s2 += __shfl_xor(s2, 1); s2 += __shfl_xor(s2, 2);
        s2 += __shfl_xor(s2, 4); s2 += __shfl_xor(s2, 8);
        float mean = s * (1.f / 256.f);
        float var  = s2 * (1.f / 256.f) - mean * mean;
        float rs = rsqrtf(var + 1e-5f);
        float4 g0a = ((const float4*)(g0 + cbase))[0];
        float4 g0b = ((const float4*)(g0 + cbase))[1];
        float4 g0c = ((const float4*)(g0 + cbase))[2];
        float4 g0d = ((const float4*)(g0 + cbase))[3];
        float4 b0a = ((const float4*)(b0 + cbase))[0];
        float4 b0b = ((const float4*)(b0 + cbase))[1];
        float4 b0c = ((const float4*)(b0 + cbase))[2];
        float4 b0d = ((const float4*)(b0 + cbase))[3];
        short8 y0, y1;
        y0[0] = f2bf((a0.x - mean) * rs * g0a.x + b0a.x);
        y0[1] = f2bf((a0.y - mean) * rs * g0a.y + b0a.y);
        y0[2] = f2bf((a0.z - mean) * rs * g0a.z + b0a.z);
        y0[3] = f2bf((a0.w - mean) * rs * g0a.w + b0a.w);
        y0[4] = f2bf((a1.x - mean) * rs * g0b.x + b0b.x);
        y0[5] = f2bf((a1.y - mean) * rs * g0b.y + b0b.y);
        y0[6] = f2bf((a1.z - mean) * rs * g0b.z + b0b.z);
        y0[7] = f2bf((a1.w - mean) * rs * g0b.w + b0b.w);
        y1[0] = f2bf((a2.x - mean) * rs * g0c.x + b0c.x);
        y1[1] = f2bf((a2.y - mean) * rs * g0c.y + b0c.y);
        y1[2] = f2bf((a2.z - mean) * rs * g0c.z + b0c.z);
        y1[3] = f2bf((a2.w - mean) * rs * g0c.w + b0c.w);
        y1[4] = f2bf((a3.x - mean) * rs * g0d.x + b0d.x);
        y1[5] = f2bf((a3.y - mean) * rs * g0d.y + b0d.y);
        y1[6] = f2bf((a3.z - mean) * rs * g0d.z + b0d.z);
        y1[7] = f2bf((a3.w - mean) * rs * g0d.w + b0d.w);
        *(short8*)(&Xs[lrow][cbase])     = y0;
        *(short8*)(&Xs[lrow][cbase + 8]) = y1;
    }
    __syncthreads();

    // ---- Phase 2: GEMM from LDS. Wave covers 16 rows x 64 cols. ----
    const int lane = tid & 63, wid = tid >> 6;
    const int m = lane & 15, quad = lane >> 4;
    const int c0 = wid * 64;

    f32x4 acc[4];
    #pragma unroll
    for (int t = 0; t < 4; t++) acc[t] = (f32x4){0.f, 0.f, 0.f, 0.f};

    for (int kk = 0; kk < 256; kk += 32) {
        short8 af = *(const short8*)(&Xs[m][kk + quad * 8]);
        #pragma unroll
        for (int t = 0; t < 4; t++) {
            short8 bf = *(const short8*)(WoT + (c0 + t * 16 + m) * 256 + kk + quad * 8);
            acc[t] = __builtin_amdgcn_mfma_f32_16x16x32_bf16(af, bf, acc[t], 0, 0, 0);
        }
    }

    // ---- Phase 3: y = x + relu(c + bo); LN1 stats over this col-quarter ----
    float s1[4] = {0.f, 0.f, 0.f, 0.f};
    float s2v[4] = {0.f, 0.f, 0.f, 0.f};
    #pragma unroll
    for (int t = 0; t < 4; t++) {
        int n = c0 + t * 16 + m;
        float bon = bo[n];
        #pragma unroll
        for (int reg = 0; reg < 4; reg++) {
            int r = quad * 4 + reg;
            float xv = bf2f(Xs[r][n]);
            float c = acc[t][reg] + bon;
            float yv = xv + (c > 0.f ? c : 0.f);
            acc[t][reg] = yv;                       // reuse acc as y storage
            s1[reg] += yv;
            s2v[reg] += yv * yv;
        }
    }
    #pragma unroll
    for (int reg = 0; reg < 4; reg++) {
        float a = s1[reg], bsum = s2v[reg];
        a += __shfl_xor(a, 1); a += __shfl_xor(a, 2); a += __shfl_xor(a, 4); a += __shfl_xor(a, 8);
        bsum += __shfl_xor(bsum, 1); bsum += __shfl_xor(bsum, 2); bsum += __shfl_xor(bsum, 4); bsum += __shfl_xor(bsum, 8);
        s1[reg] = a; s2v[reg] = bsum;
    }
    if (m == 0) {
        #pragma unroll
        for (int reg = 0; reg < 4; reg++) {
            st[wid][0][quad * 4 + reg] = s1[reg];
            st[wid][1][quad * 4 + reg] = s2v[reg];
        }
    }
    __syncthreads();
    #pragma unroll
    for (int reg = 0; reg < 4; reg++) {
        int r = quad * 4 + reg;
        float t1 = st[0][0][r] + st[1][0][r] + st[2][0][r] + st[3][0][r];
        float t2 = st[0][1][r] + st[1][1][r] + st[2][1][r] + st[3][1][r];
        float mean = t1 * (1.f / 256.f);
        float var  = t2 * (1.f / 256.f) - mean * mean;
        float rs = rsqrtf(var + 1e-5f);
        int token = r0 + r;
        #pragma unroll
        for (int t = 0; t < 4; t++) {
            int n = c0 + t * 16 + m;
            out[(size_t)token * 256 + n] = (acc[t][reg] - mean) * rs * g1[n] + b1[n];
        }
    }
}

extern "C" void kernel_launch(void* const* d_in, const int* in_sizes, int n_in,
                              void* d_out, int out_size, void* d_ws, size_t ws_size,
                              hipStream_t stream) {
    const float* Q   = (const float*)d_in[0];
    const float* K   = (const float*)d_in[1];
    const int* lengths = (const int*)d_in[2];
    const float* Wq  = (const float*)d_in[3];
    const float* bq  = (const float*)d_in[4];
    const float* Wk  = (const float*)d_in[5];
    const float* bk  = (const float*)d_in[6];
    const float* Wv  = (const float*)d_in[7];
    const float* bv  = (const float*)d_in[8];
    const float* Wo  = (const float*)d_in[9];
    const float* bo  = (const float*)d_in[10];
    const float* g0  = (const float*)d_in[11];
    const float* b0  = (const float*)d_in[12];
    const float* g1  = (const float*)d_in[13];
    const float* b1  = (const float*)d_in[14];
    float* out = (float*)d_out;

    char* ws = (char*)d_ws;
    short* qb  = (short*)(ws);                         // [8][8][1024][32] bf16, 4 MB
    short* kb  = (short*)(ws + (4u << 20));            // 4 MB
    short* vT  = (short*)(ws + (8u << 20));            // [8][8][32][1024] bf16, 4 MB
    float* O1  = (float*)(ws + (12u << 20));           // [8192][256] f32, 8 MB
    short* WqT = (short*)(ws + (20u << 20));           // 128 KB each, [n][k] bf16
    short* WkT = (short*)(ws + (20u << 20) + (128u << 10));
    short* WvT = (short*)(ws + (20u << 20) + (256u << 10));
    short* WoT = (short*)(ws + (20u << 20) + (384u << 10));

    wtrans_kernel<<<dim3(16, 4), 256, 0, stream>>>(Wq, Wk, Wv, Wo, WqT, WkT, WvT, WoT);
    proj_kernel<<<dim3(256, 2), 256, 0, stream>>>(Q, K, WqT, WkT, WvT, bq, bk, bv,
                                                  lengths, qb, kb, vT);
    attn_kernel<<<dim3(32, 64), 256, 0, stream>>>(qb, kb, vT, lengths, O1);
    out_kernel<<<dim3(512), 256, 0, stream>>>(O1, WoT, g0, b0, bo, g1, b1, out);
}

// Round 4
// 156.998 us; speedup vs baseline: 1.0652x; 1.0171x over previous
//
#include <hip/hip_runtime.h>
#include <hip/hip_bf16.h>

// Problem: B=8, N=1024, DQ=DK=DV=256, H=8, head_dim=32.
// Pipeline (all bf16 MFMA, fp32 accum):
//   K0 wtrans : W[k][n] f32 -> WT[n][k] bf16 (LDS tile transpose, coalesced both ways)
//   K1 proj   : y=0: q=(Q@Wq+bq)*mask ; y=1: k AND v from one pass over K.
//               A tile (32 rows x 256 k) staged ONCE per block in LDS as bf16
//               (coalesced f32 read, single conversion); both col-half waves
//               consume fragments from LDS. k/v share one A pass.
//               q,k stored [b][h][n][32] bf16 ; v stored transposed [b][h][32][n]
//   K2 attn   : split-K flash-style, parity-interleaved chunks (balanced for any len);
//               wave-private P tile (no block barriers in the loop), padded stride;
//               V-fragment loads hoisted above the P waitcnt (latency overlap)
//   K3 fused  : LN0(g0,b0) -> x (LDS, bf16); y = x + relu(x@Wo+bo); out = LN1(y)

typedef __attribute__((ext_vector_type(8))) short short8;
typedef __attribute__((ext_vector_type(4))) short short4v;
typedef __attribute__((ext_vector_type(4))) float f32x4;

__device__ __forceinline__ short f2bf(float f) {
    union { float f; unsigned u; } x; x.f = f;
    unsigned r = x.u + 0x7fffu + ((x.u >> 16) & 1u);   // RNE
    return (short)(r >> 16);
}
__device__ __forceinline__ float bf2f(short s) {
    union { unsigned u; float f; } x; x.u = ((unsigned)(unsigned short)s) << 16;
    return x.f;
}

// ---------------- K0: transpose + convert weights (coalesced via LDS) ----------------
// grid (16, 4): x = 64x64 tile (4x4 tiling of 256x256), y = which matrix. 256 threads.
__global__ __launch_bounds__(256) void wtrans_kernel(
    const float* __restrict__ Wq, const float* __restrict__ Wk,
    const float* __restrict__ Wv, const float* __restrict__ Wo,
    short* __restrict__ WqT, short* __restrict__ WkT,
    short* __restrict__ WvT, short* __restrict__ WoT)
{
    __shared__ short tile[64][72];                 // +8 pad: breaks pow2 stride
    const float* W; short* T;
    switch (blockIdx.y) {
        case 0:  W = Wq; T = WqT; break;
        case 1:  W = Wk; T = WkT; break;
        case 2:  W = Wv; T = WvT; break;
        default: W = Wo; T = WoT; break;
    }
    const int k0 = (blockIdx.x >> 2) * 64;         // source row tile
    const int n0 = (blockIdx.x & 3) * 64;          // source col tile
    const int c  = threadIdx.x & 63;
    const int r4 = threadIdx.x >> 6;
    #pragma unroll
    for (int i = 0; i < 16; i++) {
        int k = r4 + i * 4;
        tile[k][c] = f2bf(W[(size_t)(k0 + k) * 256 + n0 + c]);   // coalesced read
    }
    __syncthreads();
    #pragma unroll
    for (int i = 0; i < 16; i++) {
        int n = r4 + i * 4;
        T[(size_t)(n0 + n) * 256 + k0 + c] = tile[c][n];         // coalesced write
    }
}

// ---------------- K1: projections ----------------
// grid (256, 2) blocks of 256. Block: 32 token rows x 256 cols.
// y=0: q only. y=1: k AND v (one A pass, two MFMA chains).
// A tile staged in LDS bf16 once per block; wave = 16 rows x 128 cols.
__global__ __launch_bounds__(256) void proj_kernel(
    const float* __restrict__ Q, const float* __restrict__ Kin,
    const short* __restrict__ WqT, const short* __restrict__ WkT, const short* __restrict__ WvT,
    const float* __restrict__ bq, const float* __restrict__ bk, const float* __restrict__ bv,
    const int* __restrict__ lengths,
    short* __restrict__ qb, short* __restrict__ kb, short* __restrict__ vT)
{
    __shared__ short Xt[32][264];                 // A tile bf16; 264: row stride 528B -> 2-way (free)
    const int which = blockIdx.y;                 // 0=q, 1=k+v
    const float* A   = (which == 0) ? Q   : Kin;
    const short* WTa = (which == 0) ? WqT : WkT;

    const int tid = threadIdx.x;
    const int b = blockIdx.x >> 5;                // batch (32 rows/block, 32 blocks/batch)
    const int len = lengths[b];
    const int r0b = blockIdx.x * 32;              // block's token row base (global)
    const int ntok0b = r0b & 1023;                // within-batch row base of block

    // ---- stage A tile: 32 rows x 256 cols, f32 -> bf16, coalesced, converted once ----
    if (ntok0b < len) {
        #pragma unroll
        for (int it = 0; it < 8; it++) {
            int e = tid + it * 256;               // 2048 float4 loads total
            int row = e >> 6, c4 = (e & 63) * 4;
            float4 f = *(const float4*)(A + (size_t)(r0b + row) * 256 + c4);
            short4v s4;
            s4[0] = f2bf(f.x); s4[1] = f2bf(f.y); s4[2] = f2bf(f.z); s4[3] = f2bf(f.w);
            *(short4v*)(&Xt[row][c4]) = s4;
        }
    }
    __syncthreads();

    const int lane = tid & 63, wid = tid >> 6;
    const int m = lane & 15, quad = lane >> 4;
    const int rh = wid >> 1, ch = wid & 1;
    const int c0 = ch * 128;                      // wave's column base
    const int ntok0 = ntok0b + rh * 16;           // wave's within-batch row base

    f32x4 accA[8], accB[8];
    #pragma unroll
    for (int t = 0; t < 8; t++) {
        accA[t] = (f32x4){0.f, 0.f, 0.f, 0.f};
        accB[t] = (f32x4){0.f, 0.f, 0.f, 0.f};
    }

    if (ntok0 < len) {                            // fully-masked wave tiles: skip GEMM
        for (int kk = 0; kk < 256; kk += 32) {
            short8 af = *(const short8*)(&Xt[rh * 16 + m][kk + quad * 8]);
            #pragma unroll
            for (int t = 0; t < 8; t++) {
                short8 bfa = *(const short8*)(WTa + (c0 + t * 16 + m) * 256 + kk + quad * 8);
                accA[t] = __builtin_amdgcn_mfma_f32_16x16x32_bf16(af, bfa, accA[t], 0, 0, 0);
            }
            if (which == 1) {
                #pragma unroll
                for (int t = 0; t < 8; t++) {
                    short8 bfb = *(const short8*)(WvT + (c0 + t * 16 + m) * 256 + kk + quad * 8);
                    accB[t] = __builtin_amdgcn_mfma_f32_16x16x32_bf16(af, bfb, accB[t], 0, 0, 0);
                }
            }
        }
    }

    #pragma unroll
    for (int t = 0; t < 8; t++) {
        int n = c0 + t * 16 + m;                   // output column
        int h = n >> 5, i = n & 31;
        int bh = b * 8 + h;
        if (which == 0) {
            float bias = bq[n];
            #pragma unroll
            for (int reg = 0; reg < 4; reg++) {
                int ntok = ntok0 + quad * 4 + reg; // C layout: row = quad*4+reg
                float val = (ntok < len) ? (accA[t][reg] + bias) : 0.f;
                qb[((size_t)bh * 1024 + ntok) * 32 + i] = f2bf(val);
            }
        } else {
            float bk_ = bk[n];
            float bv_ = bv[n];
            #pragma unroll
            for (int reg = 0; reg < 4; reg++) {
                int ntok = ntok0 + quad * 4 + reg;
                bool ok = ntok < len;
                float vk = ok ? (accA[t][reg] + bk_) : 0.f;
                float vv = ok ? (accB[t][reg] + bv_) : 0.f;
                kb[((size_t)bh * 1024 + ntok) * 32 + i] = f2bf(vk);
                vT[(size_t)(bh * 32 + i) * 1024 + ntok] = f2bf(vv);
            }
        }
    }
}

// ---------------- K2: attention ----------------
// grid (32, 64): x = q-tile (32 rows), y = b*8+h. Block 256 = 4 waves.
// Wave (qh, ks): q-rows [qr0, qr0+16); key chunks parity-interleaved by ks
// (key0 = (2*ci+ks)*64) so both waves get ceil/floor(nch/2) regardless of len.
// No barriers in the key loop (P is wave-private); one barrier for split-K combine.
__global__ __launch_bounds__(256) void attn_kernel(
    const short* __restrict__ qb, const short* __restrict__ kb, const short* __restrict__ vT,
    const int* __restrict__ lengths, float* __restrict__ O1)
{
    __shared__ short P[4][16][72];                 // per-wave P tile, padded (72 shorts/row)
    __shared__ float cbO[2][16][33];               // split-K partial O from ks=1 waves
    __shared__ float cbL[2][16];                   // split-K partial rowsums
    const int tid = threadIdx.x;
    const int lane = tid & 63, wid = tid >> 6;
    const int m = lane & 15, quad = lane >> 4;
    const int ks = wid & 1, qh = wid >> 1;
    const int bh = blockIdx.y;
    const int b = bh >> 3, h = bh & 7;
    const int len = lengths[b];
    const int qr0 = blockIdx.x * 32 + qh * 16;

    const short* qbase = qb + (size_t)bh * 1024 * 32;
    const short* kbase = kb + (size_t)bh * 1024 * 32;
    const short* vbase = vT + (size_t)bh * 32 * 1024;

    // A-frag of q: rows qr0..qr0+15, k-dim 32 == one MFMA K step. Load once.
    const short8 qf = *(const short8*)(qbase + (qr0 + m) * 32 + quad * 8);

    f32x4 o0 = (f32x4){0.f, 0.f, 0.f, 0.f};       // vdims 0..15
    f32x4 o1 = (f32x4){0.f, 0.f, 0.f, 0.f};       // vdims 16..31
    float l[4] = {0.f, 0.f, 0.f, 0.f};            // rowsum partials (row = quad*4+reg)

    int nch = 0;
    if (qr0 < len) nch = (len + 63) >> 6;          // total 64-key chunks
    const int kchunks = (nch + 1 - ks) >> 1;       // ks=0: ceil(nch/2), ks=1: floor

    for (int ci = 0; ci < kchunks; ci++) {
        int key0 = (ci * 2 + ks) * 64;
        // V fragments are independent of P: issue them now so their L2 latency
        // hides under the QK^T + exp + P-write phase instead of after the waitcnt.
        short8 vf0a = *(const short8*)(vbase + (size_t)(m) * 1024      + key0 + quad * 8);
        short8 vf1a = *(const short8*)(vbase + (size_t)(16 + m) * 1024 + key0 + quad * 8);
        short8 vf0b = *(const short8*)(vbase + (size_t)(m) * 1024      + key0 + 32 + quad * 8);
        short8 vf1b = *(const short8*)(vbase + (size_t)(16 + m) * 1024 + key0 + 32 + quad * 8);
        #pragma unroll
        for (int t = 0; t < 4; t++) {
            short8 kf = *(const short8*)(kbase + (key0 + t * 16 + m) * 32 + quad * 8);
            f32x4 s = __builtin_amdgcn_mfma_f32_16x16x32_bf16(qf, kf,
                        (f32x4){0.f, 0.f, 0.f, 0.f}, 0, 0, 0);
            int col = key0 + t * 16 + m;           // key index (C layout col)
            bool cm = col < len;
            #pragma unroll
            for (int reg = 0; reg < 4; reg++) {
                float e = cm ? __expf(s[reg] * 0.0625f) : 0.f;   // /sqrt(256)
                l[reg] += e;
                P[wid][quad * 4 + reg][t * 16 + m] = f2bf(e);
            }
        }
        // wave-private tile: per-wave LDS ordering only, no block barrier
        asm volatile("s_waitcnt lgkmcnt(0)" ::: "memory");
        short8 pf0 = *(const short8*)(&P[wid][m][quad * 8]);
        short8 pf1 = *(const short8*)(&P[wid][m][32 + quad * 8]);
        o0 = __builtin_amdgcn_mfma_f32_16x16x32_bf16(pf0, vf0a, o0, 0, 0, 0);
        o1 = __builtin_amdgcn_mfma_f32_16x16x32_bf16(pf0, vf1a, o1, 0, 0, 0);
        o0 = __builtin_amdgcn_mfma_f32_16x16x32_bf16(pf1, vf0b, o0, 0, 0, 0);
        o1 = __builtin_amdgcn_mfma_f32_16x16x32_bf16(pf1, vf1b, o1, 0, 0, 0);
    }

    // reduce rowsums across the 16 lanes of each quad group
    #pragma unroll
    for (int reg = 0; reg < 4; reg++) {
        float s = l[reg];
        s += __shfl_xor(s, 1); s += __shfl_xor(s, 2);
        s += __shfl_xor(s, 4); s += __shfl_xor(s, 8);
        l[reg] = s;
    }

    // split-K combine: ks=1 publishes partials, ks=0 merges + writes out
    if (ks == 1) {
        #pragma unroll
        for (int reg = 0; reg < 4; reg++) {
            cbO[qh][quad * 4 + reg][m]      = o0[reg];
            cbO[qh][quad * 4 + reg][16 + m] = o1[reg];
        }
        if (m == 0) {
            #pragma unroll
            for (int reg = 0; reg < 4; reg++) cbL[qh][quad * 4 + reg] = l[reg];
        }
    }
    __syncthreads();
    if (ks == 0) {
        const int hbase = h * 32;
        #pragma unroll
        for (int reg = 0; reg < 4; reg++) {
            int r = quad * 4 + reg;
            o0[reg] += cbO[qh][r][m];
            o1[reg] += cbO[qh][r][16 + m];
            float lt = l[reg] + cbL[qh][r];
            int qrow = qr0 + r;                    // within-batch row
            float f = (qrow < len) ? 1.f / (lt + 1e-15f) : 0.f;
            size_t obase = ((size_t)(b * 1024 + qrow)) * 256 + hbase;
            float q0 = bf2f(qbase[qrow * 32 + m]);
            float q1 = bf2f(qbase[qrow * 32 + 16 + m]);
            O1[obase + m]      = q0 + o0[reg] * f;
            O1[obase + 16 + m] = q1 + o1[reg] * f;
        }
    }
}

// ---------------- K3: fused LN0 + output projection + relu residual + LN1 ----------------
// grid 512 blocks of 256 (4 waves). Block: 16 token rows x full 256 cols.
// Phase 1: LN0 from O1 -> normalized bf16 x staged in LDS (no global Xb).
// Phase 2: GEMM x@Wo from LDS A-fragments; wave = 16 rows x 64 cols (c0 = wid*64).
// Phase 3: y = x + relu(c+bo); LN1 row stats across 4 col-quarter waves via LDS.
__global__ __launch_bounds__(256) void out_kernel(
    const float* __restrict__ O1, const short* __restrict__ WoT,
    const float* __restrict__ g0, const float* __restrict__ b0,
    const float* __restrict__ bo, const float* __restrict__ g1, const float* __restrict__ b1,
    float* __restrict__ out)
{
    __shared__ short Xs[16][264];                  // normalized x, bf16, padded stride
    __shared__ float st[4][2][16];                 // [wave][{s1,s2}][row]
    const int tid = threadIdx.x;
    const int r0 = blockIdx.x * 16;

    // ---- Phase 1: LN0. 16 threads per row, 16 cols per thread. ----
    {
        const int lrow  = tid >> 4;                // 0..15
        const int cbase = (tid & 15) * 16;
        const float* rowp = O1 + (size_t)(r0 + lrow) * 256 + cbase;
        float4 a0 = ((const float4*)rowp)[0];
        float4 a1 = ((const float4*)rowp)[1];
        float4 a2 = ((const float4*)rowp)[2];
        float4 a3 = ((const float4*)rowp)[3];
        float s  = a0.x + a0.y + a0.z + a0.w + a1.x + a1.y + a1.z + a1.w
                 + a2.x + a2.y + a2.z + a2.w + a3.x + a3.y + a3.z + a3.w;
        float s2 = a0.x*a0.x + a0.y*a0.y + a0.z*a0.z + a0.w*a0.w
                 + a1.x*a1.x + a1.y*a1.y + a1.z*a1.z + a1.w*a1.w
                 + a2.x*a2.x + a2.y*a2.y + a2.z*a2.z + a2.w*a2.w
                 + a3.x*a3.x + a3.y*a3.y + a3.z*a3.z + a3.w*a3.w;
        // reduce across the 16 lanes of this row (lanes are 16-aligned groups)
        s  += __shfl_xor(s, 1);  s  += __shfl_xor(s, 2);
        s  += __shfl_xor(s, 4);  s  += __shfl_xor(s, 8);
        s2 += __shfl_xor(s2, 1); s2 += __shfl_xor(s2, 2);
        s2 += __shfl_xor(s2, 4); s2 += __shfl_xor(s2, 8);
        float mean = s * (1.f / 256.f);
        float var  = s2 * (1.f / 256.f) - mean * mean;
        float rs = rsqrtf(var + 1e-5f);
        float4 g0a = ((const float4*)(g0 + cbase))[0];
        float4 g0b = ((const float4*)(g0 + cbase))[1];
        float4 g0c = ((const float4*)(g0 + cbase))[2];
        float4 g0d = ((const float4*)(g0 + cbase))[3];
        float4 b0a = ((const float4*)(b0 + cbase))[0];
        float4 b0b = ((const float4*)(b0 + cbase))[1];
        float4 b0c = ((const float4*)(b0 + cbase))[2];
        float4 b0d = ((const float4*)(b0 + cbase))[3];
        short8 y0, y1;
        y0[0] = f2bf((a0.x - mean) * rs * g0a.x + b0a.x);
        y0[1] = f2bf((a0.y - mean) * rs * g0a.y + b0a.y);
        y0[2] = f2bf((a0.z - mean) * rs * g0a.z + b0a.z);
        y0[3] = f2bf((a0.w - mean) * rs * g0a.w + b0a.w);
        y0[4] = f2bf((a1.x - mean) * rs * g0b.x + b0b.x);
        y0[5] = f2bf((a1.y - mean) * rs * g0b.y + b0b.y);
        y0[6] = f2bf((a1.z - mean) * rs * g0b.z + b0b.z);
        y0[7] = f2bf((a1.w - mean) * rs * g0b.w + b0b.w);
        y1[0] = f2bf((a2.x - mean) * rs * g0c.x + b0c.x);
        y1[1] = f2bf((a2.y - mean) * rs * g0c.y + b0c.y);
        y1[2] = f2bf((a2.z - mean) * rs * g0c.z + b0c.z);
        y1[3] = f2bf((a2.w - mean) * rs * g0c.w + b0c.w);
        y1[4] = f2bf((a3.x - mean) * rs * g0d.x + b0d.x);
        y1[5] = f2bf((a3.y - mean) * rs * g0d.y + b0d.y);
        y1[6] = f2bf((a3.z - mean) * rs * g0d.z + b0d.z);
        y1[7] = f2bf((a3.w - mean) * rs * g0d.w + b0d.w);
        *(short8*)(&Xs[lrow][cbase])     = y0;
        *(short8*)(&Xs[lrow][cbase + 8]) = y1;
    }
    __syncthreads();

    // ---- Phase 2: GEMM from LDS. Wave covers 16 rows x 64 cols. ----
    const int lane = tid & 63, wid = tid >> 6;
    const int m = lane & 15, quad = lane >> 4;
    const int c0 = wid * 64;

    f32x4 acc[4];
    #pragma unroll
    for (int t = 0; t < 4; t++) acc[t] = (f32x4){0.f, 0.f, 0.f, 0.f};

    for (int kk = 0; kk < 256; kk += 32) {
        short8 af = *(const short8*)(&Xs[m][kk + quad * 8]);
        #pragma unroll
        for (int t = 0; t < 4; t++) {
            short8 bf = *(const short8*)(WoT + (c0 + t * 16 + m) * 256 + kk + quad * 8);
            acc[t] = __builtin_amdgcn_mfma_f32_16x16x32_bf16(af, bf, acc[t], 0, 0, 0);
        }
    }

    // ---- Phase 3: y = x + relu(c + bo); LN1 stats over this col-quarter ----
    float s1[4] = {0.f, 0.f, 0.f, 0.f};
    float s2v[4] = {0.f, 0.f, 0.f, 0.f};
    #pragma unroll
    for (int t = 0; t < 4; t++) {
        int n = c0 + t * 16 + m;
        float bon = bo[n];
        #pragma unroll
        for (int reg = 0; reg < 4; reg++) {
            int r = quad * 4 + reg;
            float xv = bf2f(Xs[r][n]);
            float c = acc[t][reg] + bon;
            float yv = xv + (c > 0.f ? c : 0.f);
            acc[t][reg] = yv;                       // reuse acc as y storage
            s1[reg] += yv;
            s2v[reg] += yv * yv;
        }
    }
    #pragma unroll
    for (int reg = 0; reg < 4; reg++) {
        float a = s1[reg], bsum = s2v[reg];
        a += __shfl_xor(a, 1); a += __shfl_xor(a, 2); a += __shfl_xor(a, 4); a += __shfl_xor(a, 8);
        bsum += __shfl_xor(bsum, 1); bsum += __shfl_xor(bsum, 2); bsum += __shfl_xor(bsum, 4); bsum += __shfl_xor(bsum, 8);
        s1[reg] = a; s2v[reg] = bsum;
    }
    if (m == 0) {
        #pragma unroll
        for (int reg = 0; reg < 4; reg++) {
            st[wid][0][quad * 4 + reg] = s1[reg];
            st[wid][1][quad * 4 + reg] = s2v[reg];
        }
    }
    __syncthreads();
    #pragma unroll
    for (int reg = 0; reg < 4; reg++) {
        int r = quad * 4 + reg;
        float t1 = st[0][0][r] + st[1][0][r] + st[2][0][r] + st[3][0][r];
        float t2 = st[0][1][r] + st[1][1][r] + st[2][1][r] + st[3][1][r];
        float mean = t1 * (1.f / 256.f);
        float var  = t2 * (1.f / 256.f) - mean * mean;
        float rs = rsqrtf(var + 1e-5f);
        int token = r0 + r;
        #pragma unroll
        for (int t = 0; t < 4; t++) {
            int n = c0 + t * 16 + m;
            out[(size_t)token * 256 + n] = (acc[t][reg] - mean) * rs * g1[n] + b1[n];
        }
    }
}

extern "C" void kernel_launch(void* const* d_in, const int* in_sizes, int n_in,
                              void* d_out, int out_size, void* d_ws, size_t ws_size,
                              hipStream_t stream) {
    const float* Q   = (const float*)d_in[0];
    const float* K   = (const float*)d_in[1];
    const int* lengths = (const int*)d_in[2];
    const float* Wq  = (const float*)d_in[3];
    const float* bq  = (const float*)d_in[4];
    const float* Wk  = (const float*)d_in[5];
    const float* bk  = (const float*)d_in[6];
    const float* Wv  = (const float*)d_in[7];
    const float* bv  = (const float*)d_in[8];
    const float* Wo  = (const float*)d_in[9];
    const float* bo  = (const float*)d_in[10];
    const float* g0  = (const float*)d_in[11];
    const float* b0  = (const float*)d_in[12];
    const float* g1  = (const float*)d_in[13];
    const float* b1  = (const float*)d_in[14];
    float* out = (float*)d_out;

    char* ws = (char*)d_ws;
    short* qb  = (short*)(ws);                         // [8][8][1024][32] bf16, 4 MB
    short* kb  = (short*)(ws + (4u << 20));            // 4 MB
    short* vT  = (short*)(ws + (8u << 20));            // [8][8][32][1024] bf16, 4 MB
    float* O1  = (float*)(ws + (12u << 20));           // [8192][256] f32, 8 MB
    short* WqT = (short*)(ws + (20u << 20));           // 128 KB each, [n][k] bf16
    short* WkT = (short*)(ws + (20u << 20) + (128u << 10));
    short* WvT = (short*)(ws + (20u << 20) + (256u << 10));
    short* WoT = (short*)(ws + (20u << 20) + (384u << 10));

    wtrans_kernel<<<dim3(16, 4), 256, 0, stream>>>(Wq, Wk, Wv, Wo, WqT, WkT, WvT, WoT);
    proj_kernel<<<dim3(256, 2), 256, 0, stream>>>(Q, K, WqT, WkT, WvT, bq, bk, bv,
                                                  lengths, qb, kb, vT);
    attn_kernel<<<dim3(32, 64), 256, 0, stream>>>(qb, kb, vT, lengths, O1);
    out_kernel<<<dim3(512), 256, 0, stream>>>(O1, WoT, g0, b0, bo, g1, b1, out);
}

// Round 5
// 150.220 us; speedup vs baseline: 1.1132x; 1.0451x over previous
//
#include <hip/hip_runtime.h>
#include <hip/hip_bf16.h>

// Problem: B=8, N=1024, DQ=DK=DV=256, H=8, head_dim=32.
// Pipeline (all bf16 MFMA, fp32 accum):
//   K0 wtrans : W[k][n] f32 -> WT[n][k] bf16 (LDS tile transpose, coalesced both ways)
//   K1 proj   : y=0: q=(Q@Wq+bq)*mask ; y=1: k AND v from one pass over K.
//               A tile staged once per block in LDS bf16; k pre-scaled by 1/sqrt(DV)
//               (kb feeds only QK^T). q,k: [b][h][n][32] ; v: [b][h][32][n] (transposed)
//   K2 attn   : 64 q-rows/block = 4 qh-waves sharing K/V chunks via double-buffered LDS
//               (K,V read ONCE per block from L2: 4x traffic cut vs split-K version);
//               next-chunk loads issued before the barrier (latency hidden under compute);
//               one barrier/chunk; wave-private P tile; direct per-wave epilogue.
//   K3 fused  : LN0(g0,b0) -> x (LDS, bf16); y = x + relu(x@Wo+bo); out = LN1(y)

typedef __attribute__((ext_vector_type(8))) short short8;
typedef __attribute__((ext_vector_type(4))) short short4v;
typedef __attribute__((ext_vector_type(4))) float f32x4;

__device__ __forceinline__ short f2bf(float f) {
    union { float f; unsigned u; } x; x.f = f;
    unsigned r = x.u + 0x7fffu + ((x.u >> 16) & 1u);   // RNE
    return (short)(r >> 16);
}
__device__ __forceinline__ float bf2f(short s) {
    union { unsigned u; float f; } x; x.u = ((unsigned)(unsigned short)s) << 16;
    return x.f;
}

// ---------------- K0: transpose + convert weights (coalesced via LDS) ----------------
// grid (16, 4): x = 64x64 tile (4x4 tiling of 256x256), y = which matrix. 256 threads.
__global__ __launch_bounds__(256) void wtrans_kernel(
    const float* __restrict__ Wq, const float* __restrict__ Wk,
    const float* __restrict__ Wv, const float* __restrict__ Wo,
    short* __restrict__ WqT, short* __restrict__ WkT,
    short* __restrict__ WvT, short* __restrict__ WoT)
{
    __shared__ short tile[64][72];                 // +8 pad: breaks pow2 stride
    const float* W; short* T;
    switch (blockIdx.y) {
        case 0:  W = Wq; T = WqT; break;
        case 1:  W = Wk; T = WkT; break;
        case 2:  W = Wv; T = WvT; break;
        default: W = Wo; T = WoT; break;
    }
    const int k0 = (blockIdx.x >> 2) * 64;         // source row tile
    const int n0 = (blockIdx.x & 3) * 64;          // source col tile
    const int c  = threadIdx.x & 63;
    const int r4 = threadIdx.x >> 6;
    #pragma unroll
    for (int i = 0; i < 16; i++) {
        int k = r4 + i * 4;
        tile[k][c] = f2bf(W[(size_t)(k0 + k) * 256 + n0 + c]);   // coalesced read
    }
    __syncthreads();
    #pragma unroll
    for (int i = 0; i < 16; i++) {
        int n = r4 + i * 4;
        T[(size_t)(n0 + n) * 256 + k0 + c] = tile[c][n];         // coalesced write
    }
}

// ---------------- K1: projections ----------------
// grid (256, 2) blocks of 256. Block: 32 token rows x 256 cols.
// y=0: q only. y=1: k AND v (one A pass, two MFMA chains). A tile staged in LDS.
__global__ __launch_bounds__(256) void proj_kernel(
    const float* __restrict__ Q, const float* __restrict__ Kin,
    const short* __restrict__ WqT, const short* __restrict__ WkT, const short* __restrict__ WvT,
    const float* __restrict__ bq, const float* __restrict__ bk, const float* __restrict__ bv,
    const int* __restrict__ lengths,
    short* __restrict__ qb, short* __restrict__ kb, short* __restrict__ vT)
{
    __shared__ short Xt[32][264];                 // A tile bf16; stride 528B -> 2-way (free)
    const int which = blockIdx.y;                 // 0=q, 1=k+v
    const float* A   = (which == 0) ? Q   : Kin;
    const short* WTa = (which == 0) ? WqT : WkT;

    const int tid = threadIdx.x;
    const int b = blockIdx.x >> 5;                // batch (32 rows/block, 32 blocks/batch)
    const int len = lengths[b];
    const int r0b = blockIdx.x * 32;              // block's token row base (global)
    const int ntok0b = r0b & 1023;                // within-batch row base of block

    // ---- stage A tile: 32 rows x 256 cols, f32 -> bf16, coalesced, converted once ----
    if (ntok0b < len) {
        #pragma unroll
        for (int it = 0; it < 8; it++) {
            int e = tid + it * 256;               // 2048 float4 loads total
            int row = e >> 6, c4 = (e & 63) * 4;
            float4 f = *(const float4*)(A + (size_t)(r0b + row) * 256 + c4);
            short4v s4;
            s4[0] = f2bf(f.x); s4[1] = f2bf(f.y); s4[2] = f2bf(f.z); s4[3] = f2bf(f.w);
            *(short4v*)(&Xt[row][c4]) = s4;
        }
    }
    __syncthreads();

    const int lane = tid & 63, wid = tid >> 6;
    const int m = lane & 15, quad = lane >> 4;
    const int rh = wid >> 1, ch = wid & 1;
    const int c0 = ch * 128;                      // wave's column base
    const int ntok0 = ntok0b + rh * 16;           // wave's within-batch row base

    f32x4 accA[8], accB[8];
    #pragma unroll
    for (int t = 0; t < 8; t++) {
        accA[t] = (f32x4){0.f, 0.f, 0.f, 0.f};
        accB[t] = (f32x4){0.f, 0.f, 0.f, 0.f};
    }

    if (ntok0 < len) {                            // fully-masked wave tiles: skip GEMM
        for (int kk = 0; kk < 256; kk += 32) {
            short8 af = *(const short8*)(&Xt[rh * 16 + m][kk + quad * 8]);
            #pragma unroll
            for (int t = 0; t < 8; t++) {
                short8 bfa = *(const short8*)(WTa + (c0 + t * 16 + m) * 256 + kk + quad * 8);
                accA[t] = __builtin_amdgcn_mfma_f32_16x16x32_bf16(af, bfa, accA[t], 0, 0, 0);
            }
            if (which == 1) {
                #pragma unroll
                for (int t = 0; t < 8; t++) {
                    short8 bfb = *(const short8*)(WvT + (c0 + t * 16 + m) * 256 + kk + quad * 8);
                    accB[t] = __builtin_amdgcn_mfma_f32_16x16x32_bf16(af, bfb, accB[t], 0, 0, 0);
                }
            }
        }
    }

    const float KSCALE = 0.0625f;                  // 1/sqrt(256), folded into kb
    #pragma unroll
    for (int t = 0; t < 8; t++) {
        int n = c0 + t * 16 + m;                   // output column
        int h = n >> 5, i = n & 31;
        int bh = b * 8 + h;
        if (which == 0) {
            float bias = bq[n];
            #pragma unroll
            for (int reg = 0; reg < 4; reg++) {
                int ntok = ntok0 + quad * 4 + reg; // C layout: row = quad*4+reg
                float val = (ntok < len) ? (accA[t][reg] + bias) : 0.f;
                qb[((size_t)bh * 1024 + ntok) * 32 + i] = f2bf(val);
            }
        } else {
            float bk_ = bk[n];
            float bv_ = bv[n];
            #pragma unroll
            for (int reg = 0; reg < 4; reg++) {
                int ntok = ntok0 + quad * 4 + reg;
                bool ok = ntok < len;
                float vk = ok ? (accA[t][reg] + bk_) * KSCALE : 0.f;
                float vv = ok ? (accB[t][reg] + bv_) : 0.f;
                kb[((size_t)bh * 1024 + ntok) * 32 + i] = f2bf(vk);
                vT[(size_t)(bh * 32 + i) * 1024 + ntok] = f2bf(vv);
            }
        }
    }
}

// ---------------- K2: attention ----------------
// grid (16, 64): x = 64-row q-tile, y = b*8+h. Block 256 = 4 waves; wave wid owns
// q-rows [bx*64 + wid*16, +16). All waves share each 64-key K/V chunk, staged in
// double-buffered LDS (read once per block from L2). One barrier per chunk;
// next-chunk global loads issued before the barrier so L2/HBM latency hides
// under the current chunk's compute. P tile stays wave-private.
__global__ __launch_bounds__(256) void attn_kernel(
    const short* __restrict__ qb, const short* __restrict__ kb, const short* __restrict__ vT,
    const int* __restrict__ lengths, float* __restrict__ O1)
{
    __shared__ short Kb[2][64][36];                // 9216 B  (row stride 18 dw: <=2-way)
    __shared__ short Vb[2][32][76];                // 9728 B  (row stride 38 dw: ~2-way)
    __shared__ short P[4][16][72];                 // 9216 B  (wave-private)
    const int tid = threadIdx.x;
    const int lane = tid & 63, wid = tid >> 6;
    const int m = lane & 15, quad = lane >> 4;
    const int bh = blockIdx.y;
    const int b = bh >> 3, h = bh & 7;
    const int len = lengths[b];
    const int qr0 = blockIdx.x * 64 + wid * 16;
    const bool active = qr0 < len;

    const short* qbase = qb + (size_t)bh * 1024 * 32;
    const short* kbase = kb + (size_t)bh * 1024 * 32;
    const short* vbase = vT + (size_t)bh * 32 * 1024;

    // A-frag of q: rows qr0..qr0+15, k-dim 32 == one MFMA K step. Load once.
    const short8 qf = *(const short8*)(qbase + (qr0 + m) * 32 + quad * 8);

    f32x4 o0 = (f32x4){0.f, 0.f, 0.f, 0.f};       // vdims 0..15
    f32x4 o1 = (f32x4){0.f, 0.f, 0.f, 0.f};       // vdims 16..31
    float l[4] = {0.f, 0.f, 0.f, 0.f};            // rowsum partials (row = quad*4+reg)

    // block-uniform chunk count (block skips entirely if its 64 rows are all masked)
    const int nch = (blockIdx.x * 64 < len) ? ((len + 63) >> 6) : 0;

    short8 kr, vr;
    if (nch > 0) {                                 // prologue loads for chunk 0
        kr = *(const short8*)(kbase + tid * 8);
        vr = *(const short8*)(vbase + (size_t)(tid >> 3) * 1024 + (tid & 7) * 8);
    }

    for (int ci = 0; ci < nch; ci++) {
        const int buf = ci & 1;
        // stage current chunk (regs -> LDS); K: row tid>>2, V: row tid>>3
        *(short8*)(&Kb[buf][tid >> 2][(tid & 3) * 8]) = kr;
        *(short8*)(&Vb[buf][tid >> 3][(tid & 7) * 8]) = vr;
        if (ci + 1 < nch) {                        // issue next chunk's loads now
            int k1 = (ci + 1) * 64;
            kr = *(const short8*)(kbase + k1 * 32 + tid * 8);
            vr = *(const short8*)(vbase + (size_t)(tid >> 3) * 1024 + k1 + (tid & 7) * 8);
        }
        __syncthreads();                           // staged chunk visible to all waves

        if (active) {
            const int key0 = ci * 64;
            #pragma unroll
            for (int t = 0; t < 4; t++) {
                short8 kf = *(const short8*)(&Kb[buf][t * 16 + m][quad * 8]);
                f32x4 s = __builtin_amdgcn_mfma_f32_16x16x32_bf16(qf, kf,
                            (f32x4){0.f, 0.f, 0.f, 0.f}, 0, 0, 0);
                int col = key0 + t * 16 + m;       // key index (C layout col)
                bool cm = col < len;
                #pragma unroll
                for (int reg = 0; reg < 4; reg++) {
                    float e = cm ? __expf(s[reg]) : 0.f;   // scale pre-folded into kb
                    l[reg] += e;
                    P[wid][quad * 4 + reg][t * 16 + m] = f2bf(e);
                }
            }
            // wave-private P ordering only (no block barrier)
            asm volatile("s_waitcnt lgkmcnt(0)" ::: "memory");
            #pragma unroll
            for (int c = 0; c < 2; c++) {
                short8 pf  = *(const short8*)(&P[wid][m][c * 32 + quad * 8]);
                short8 vf0 = *(const short8*)(&Vb[buf][m][c * 32 + quad * 8]);
                short8 vf1 = *(const short8*)(&Vb[buf][16 + m][c * 32 + quad * 8]);
                o0 = __builtin_amdgcn_mfma_f32_16x16x32_bf16(pf, vf0, o0, 0, 0, 0);
                o1 = __builtin_amdgcn_mfma_f32_16x16x32_bf16(pf, vf1, o1, 0, 0, 0);
            }
        }
    }

    // reduce rowsums across the 16 lanes of each quad group
    #pragma unroll
    for (int reg = 0; reg < 4; reg++) {
        float s = l[reg];
        s += __shfl_xor(s, 1); s += __shfl_xor(s, 2);
        s += __shfl_xor(s, 4); s += __shfl_xor(s, 8);
        l[reg] = s;
    }

    // direct per-wave epilogue (each wave owns its 16 q-rows; no split-K combine)
    const int hbase = h * 32;
    #pragma unroll
    for (int reg = 0; reg < 4; reg++) {
        int qrow = qr0 + quad * 4 + reg;           // within-batch row (C layout)
        float f = (qrow < len) ? 1.f / (l[reg] + 1e-15f) : 0.f;
        size_t obase = ((size_t)(b * 1024 + qrow)) * 256 + hbase;
        float q0 = bf2f(qbase[qrow * 32 + m]);
        float q1 = bf2f(qbase[qrow * 32 + 16 + m]);
        O1[obase + m]      = q0 + o0[reg] * f;
        O1[obase + 16 + m] = q1 + o1[reg] * f;
    }
}

// ---------------- K3: fused LN0 + output projection + relu residual + LN1 ----------------
// grid 512 blocks of 256 (4 waves). Block: 16 token rows x full 256 cols.
// Phase 1: LN0 from O1 -> normalized bf16 x staged in LDS (no global Xb).
// Phase 2: GEMM x@Wo from LDS A-fragments; wave = 16 rows x 64 cols (c0 = wid*64).
// Phase 3: y = x + relu(c+bo); LN1 row stats across 4 col-quarter waves via LDS.
__global__ __launch_bounds__(256) void out_kernel(
    const float* __restrict__ O1, const short* __restrict__ WoT,
    const float* __restrict__ g0, const float* __restrict__ b0,
    const float* __restrict__ bo, const float* __restrict__ g1, const float* __restrict__ b1,
    float* __restrict__ out)
{
    __shared__ short Xs[16][264];                  // normalized x, bf16, padded stride
    __shared__ float st[4][2][16];                 // [wave][{s1,s2}][row]
    const int tid = threadIdx.x;
    const int r0 = blockIdx.x * 16;

    // ---- Phase 1: LN0. 16 threads per row, 16 cols per thread. ----
    {
        const int lrow  = tid >> 4;                // 0..15
        const int cbase = (tid & 15) * 16;
        const float* rowp = O1 + (size_t)(r0 + lrow) * 256 + cbase;
        float4 a0 = ((const float4*)rowp)[0];
        float4 a1 = ((const float4*)rowp)[1];
        float4 a2 = ((const float4*)rowp)[2];
        float4 a3 = ((const float4*)rowp)[3];
        float s  = a0.x + a0.y + a0.z + a0.w + a1.x + a1.y + a1.z + a1.w
                 + a2.x + a2.y + a2.z + a2.w + a3.x + a3.y + a3.z + a3.w;
        float s2 = a0.x*a0.x + a0.y*a0.y + a0.z*a0.z + a0.w*a0.w
                 + a1.x*a1.x + a1.y*a1.y + a1.z*a1.z + a1.w*a1.w
                 + a2.x*a2.x + a2.y*a2.y + a2.z*a2.z + a2.w*a2.w
                 + a3.x*a3.x + a3.y*a3.y + a3.z*a3.z + a3.w*a3.w;
        // reduce across the 16 lanes of this row (lanes are 16-aligned groups)
        s  += __shfl_xor(s, 1);  s  += __shfl_xor(s, 2);
        s  += __shfl_xor(s, 4);  s  += __shfl_xor(s, 8);
        s2 += __shfl_xor(s2, 1); s2 += __shfl_xor(s2, 2);
        s2 += __shfl_xor(s2, 4); s2 += __shfl_xor(s2, 8);
        float mean = s * (1.f / 256.f);
        float var  = s2 * (1.f / 256.f) - mean * mean;
        float rs = rsqrtf(var + 1e-5f);
        float4 g0a = ((const float4*)(g0 + cbase))[0];
        float4 g0b = ((const float4*)(g0 + cbase))[1];
        float4 g0c = ((const float4*)(g0 + cbase))[2];
        float4 g0d = ((const float4*)(g0 + cbase))[3];
        float4 b0a = ((const float4*)(b0 + cbase))[0];
        float4 b0b = ((const float4*)(b0 + cbase))[1];
        float4 b0c = ((const float4*)(b0 + cbase))[2];
        float4 b0d = ((const float4*)(b0 + cbase))[3];
        short8 y0, y1;
        y0[0] = f2bf((a0.x - mean) * rs * g0a.x + b0a.x);
        y0[1] = f2bf((a0.y - mean) * rs * g0a.y + b0a.y);
        y0[2] = f2bf((a0.z - mean) * rs * g0a.z + b0a.z);
        y0[3] = f2bf((a0.w - mean) * rs * g0a.w + b0a.w);
        y0[4] = f2bf((a1.x - mean) * rs * g0b.x + b0b.x);
        y0[5] = f2bf((a1.y - mean) * rs * g0b.y + b0b.y);
        y0[6] = f2bf((a1.z - mean) * rs * g0b.z + b0b.z);
        y0[7] = f2bf((a1.w - mean) * rs * g0b.w + b0b.w);
        y1[0] = f2bf((a2.x - mean) * rs * g0c.x + b0c.x);
        y1[1] = f2bf((a2.y - mean) * rs * g0c.y + b0c.y);
        y1[2] = f2bf((a2.z - mean) * rs * g0c.z + b0c.z);
        y1[3] = f2bf((a2.w - mean) * rs * g0c.w + b0c.w);
        y1[4] = f2bf((a3.x - mean) * rs * g0d.x + b0d.x);
        y1[5] = f2bf((a3.y - mean) * rs * g0d.y + b0d.y);
        y1[6] = f2bf((a3.z - mean) * rs * g0d.z + b0d.z);
        y1[7] = f2bf((a3.w - mean) * rs * g0d.w + b0d.w);
        *(short8*)(&Xs[lrow][cbase])     = y0;
        *(short8*)(&Xs[lrow][cbase + 8]) = y1;
    }
    __syncthreads();

    // ---- Phase 2: GEMM from LDS. Wave covers 16 rows x 64 cols. ----
    const int lane = tid & 63, wid = tid >> 6;
    const int m = lane & 15, quad = lane >> 4;
    const int c0 = wid * 64;

    f32x4 acc[4];
    #pragma unroll
    for (int t = 0; t < 4; t++) acc[t] = (f32x4){0.f, 0.f, 0.f, 0.f};

    for (int kk = 0; kk < 256; kk += 32) {
        short8 af = *(const short8*)(&Xs[m][kk + quad * 8]);
        #pragma unroll
        for (int t = 0; t < 4; t++) {
            short8 bf = *(const short8*)(WoT + (c0 + t * 16 + m) * 256 + kk + quad * 8);
            acc[t] = __builtin_amdgcn_mfma_f32_16x16x32_bf16(af, bf, acc[t], 0, 0, 0);
        }
    }

    // ---- Phase 3: y = x + relu(c + bo); LN1 stats over this col-quarter ----
    float s1[4] = {0.f, 0.f, 0.f, 0.f};
    float s2v[4] = {0.f, 0.f, 0.f, 0.f};
    #pragma unroll
    for (int t = 0; t < 4; t++) {
        int n = c0 + t * 16 + m;
        float bon = bo[n];
        #pragma unroll
        for (int reg = 0; reg < 4; reg++) {
            int r = quad * 4 + reg;
            float xv = bf2f(Xs[r][n]);
            float c = acc[t][reg] + bon;
            float yv = xv + (c > 0.f ? c : 0.f);
            acc[t][reg] = yv;                       // reuse acc as y storage
            s1[reg] += yv;
            s2v[reg] += yv * yv;
        }
    }
    #pragma unroll
    for (int reg = 0; reg < 4; reg++) {
        float a = s1[reg], bsum = s2v[reg];
        a += __shfl_xor(a, 1); a += __shfl_xor(a, 2); a += __shfl_xor(a, 4); a += __shfl_xor(a, 8);
        bsum += __shfl_xor(bsum, 1); bsum += __shfl_xor(bsum, 2); bsum += __shfl_xor(bsum, 4); bsum += __shfl_xor(bsum, 8);
        s1[reg] = a; s2v[reg] = bsum;
    }
    if (m == 0) {
        #pragma unroll
        for (int reg = 0; reg < 4; reg++) {
            st[wid][0][quad * 4 + reg] = s1[reg];
            st[wid][1][quad * 4 + reg] = s2v[reg];
        }
    }
    __syncthreads();
    #pragma unroll
    for (int reg = 0; reg < 4; reg++) {
        int r = quad * 4 + reg;
        float t1 = st[0][0][r] + st[1][0][r] + st[2][0][r] + st[3][0][r];
        float t2 = st[0][1][r] + st[1][1][r] + st[2][1][r] + st[3][1][r];
        float mean = t1 * (1.f / 256.f);
        float var  = t2 * (1.f / 256.f) - mean * mean;
        float rs = rsqrtf(var + 1e-5f);
        int token = r0 + r;
        #pragma unroll
        for (int t = 0; t < 4; t++) {
            int n = c0 + t * 16 + m;
            out[(size_t)token * 256 + n] = (acc[t][reg] - mean) * rs * g1[n] + b1[n];
        }
    }
}

extern "C" void kernel_launch(void* const* d_in, const int* in_sizes, int n_in,
                              void* d_out, int out_size, void* d_ws, size_t ws_size,
                              hipStream_t stream) {
    const float* Q   = (const float*)d_in[0];
    const float* K   = (const float*)d_in[1];
    const int* lengths = (const int*)d_in[2];
    const float* Wq  = (const float*)d_in[3];
    const float* bq  = (const float*)d_in[4];
    const float* Wk  = (const float*)d_in[5];
    const float* bk  = (const float*)d_in[6];
    const float* Wv  = (const float*)d_in[7];
    const float* bv  = (const float*)d_in[8];
    const float* Wo  = (const float*)d_in[9];
    const float* bo  = (const float*)d_in[10];
    const float* g0  = (const float*)d_in[11];
    const float* b0  = (const float*)d_in[12];
    const float* g1  = (const float*)d_in[13];
    const float* b1  = (const float*)d_in[14];
    float* out = (float*)d_out;

    char* ws = (char*)d_ws;
    short* qb  = (short*)(ws);                         // [8][8][1024][32] bf16, 4 MB
    short* kb  = (short*)(ws + (4u << 20));            // 4 MB (pre-scaled by 1/16)
    short* vT  = (short*)(ws + (8u << 20));            // [8][8][32][1024] bf16, 4 MB
    float* O1  = (float*)(ws + (12u << 20));           // [8192][256] f32, 8 MB
    short* WqT = (short*)(ws + (20u << 20));           // 128 KB each, [n][k] bf16
    short* WkT = (short*)(ws + (20u << 20) + (128u << 10));
    short* WvT = (short*)(ws + (20u << 20) + (256u << 10));
    short* WoT = (short*)(ws + (20u << 20) + (384u << 10));

    wtrans_kernel<<<dim3(16, 4), 256, 0, stream>>>(Wq, Wk, Wv, Wo, WqT, WkT, WvT, WoT);
    proj_kernel<<<dim3(256, 2), 256, 0, stream>>>(Q, K, WqT, WkT, WvT, bq, bk, bv,
                                                  lengths, qb, kb, vT);
    attn_kernel<<<dim3(16, 64), 256, 0, stream>>>(qb, kb, vT, lengths, O1);
    out_kernel<<<dim3(512), 256, 0, stream>>>(O1, WoT, g0, b0, bo, g1, b1, out);
}